// Round 1
// baseline (2636.124 us; speedup 1.0000x reference)
//
#include <hip/hip_runtime.h>
#include <math.h>

#define N_NODES 100000
#define N_EDGES 300000
#define N_GRAPHS 2048
#define HIDDEN 256
#define NODE_IN 64
#define N_LAYERS 3
#define LN_EPS 1e-5f
#define TILE 32

__device__ __forceinline__ float silu_f(float x) {
    return x / (1.f + expf(-x));
}

// h = silu(x @ W_in + b_in)   [N_NODES, HIDDEN]
__global__ __launch_bounds__(256) void input_proj(
        const float* __restrict__ x, const float* __restrict__ Win,
        const float* __restrict__ bin, float* __restrict__ h) {
    __shared__ __align__(16) float Wl[NODE_IN * HIDDEN];  // 64 KB
    __shared__ float xr[NODE_IN];
    const int t = threadIdx.x;
    for (int i = t; i < NODE_IN * HIDDEN; i += 256) Wl[i] = Win[i];
    const float bias = bin[t];
    __syncthreads();
    for (int node = blockIdx.x; node < N_NODES; node += gridDim.x) {
        if (t < NODE_IN) xr[t] = x[node * NODE_IN + t];
        __syncthreads();
        float acc = bias;
        #pragma unroll
        for (int k0 = 0; k0 < NODE_IN; k0 += 4) {
            float4 a = *reinterpret_cast<const float4*>(&xr[k0]);
            acc += a.x * Wl[(k0 + 0) * HIDDEN + t];
            acc += a.y * Wl[(k0 + 1) * HIDDEN + t];
            acc += a.z * Wl[(k0 + 2) * HIDDEN + t];
            acc += a.w * Wl[(k0 + 3) * HIDDEN + t];
        }
        h[(size_t)node * HIDDEN + t] = silu_f(acc);
        __syncthreads();
    }
}

// msg[dst] += relu(h[src]) for each edge; one block per edge
__global__ __launch_bounds__(256) void scatter_relu(
        const float* __restrict__ h, const int* __restrict__ src,
        const int* __restrict__ dst, float* __restrict__ msg) {
    const int e = blockIdx.x;
    const int t = threadIdx.x;
    const int s = src[e];
    const int d = dst[e];
    float v = h[(size_t)s * HIDDEN + t];
    if (v > 0.f) atomicAdd(&msg[(size_t)d * HIDDEN + t], v);
}

// out = silu(LN((h + msg) @ W + b) * gamma + beta) + h
// 32-node tile per block; thread t owns output column t; acc[32] in regs.
__global__ __launch_bounds__(256) void gemm_ln(
        const float* __restrict__ h, const float* __restrict__ msg,
        const float* __restrict__ W, const float* __restrict__ bias,
        const float* __restrict__ gamma, const float* __restrict__ beta,
        float* __restrict__ out) {
    __shared__ __align__(16) float tile[TILE * HIDDEN];  // 32 KB
    __shared__ float mu_s[TILE], rs_s[TILE];
    const int t = threadIdx.x;
    const size_t base = (size_t)blockIdx.x * TILE * HIDDEN;

    // load agg = h + msg for 32 rows
    #pragma unroll
    for (int r = 0; r < TILE; ++r) {
        size_t idx = base + (size_t)r * HIDDEN + t;
        tile[r * HIDDEN + t] = h[idx] + msg[idx];
    }
    __syncthreads();

    float acc[TILE];
    #pragma unroll
    for (int r = 0; r < TILE; ++r) acc[r] = 0.f;

    for (int k0 = 0; k0 < HIDDEN; k0 += 4) {
        const float w0 = W[(k0 + 0) * HIDDEN + t];
        const float w1 = W[(k0 + 1) * HIDDEN + t];
        const float w2 = W[(k0 + 2) * HIDDEN + t];
        const float w3 = W[(k0 + 3) * HIDDEN + t];
        #pragma unroll
        for (int r = 0; r < TILE; ++r) {
            float4 a = *reinterpret_cast<const float4*>(&tile[r * HIDDEN + k0]);
            acc[r] += a.x * w0;
            acc[r] += a.y * w1;
            acc[r] += a.z * w2;
            acc[r] += a.w * w3;
        }
    }
    __syncthreads();  // done reading agg; reuse tile for h2

    const float bs = bias[t];
    #pragma unroll
    for (int r = 0; r < TILE; ++r) tile[r * HIDDEN + t] = acc[r] + bs;
    __syncthreads();

    // LN stats: 8 threads per node (two-pass for accuracy)
    {
        const int n = t >> 3, j = t & 7;
        float s = 0.f;
        #pragma unroll
        for (int i = 0; i < HIDDEN / 8; ++i) s += tile[n * HIDDEN + j + 8 * i];
        s += __shfl_xor(s, 1); s += __shfl_xor(s, 2); s += __shfl_xor(s, 4);
        const float mu = s * (1.f / HIDDEN);
        float v = 0.f;
        #pragma unroll
        for (int i = 0; i < HIDDEN / 8; ++i) {
            float d = tile[n * HIDDEN + j + 8 * i] - mu;
            v += d * d;
        }
        v += __shfl_xor(v, 1); v += __shfl_xor(v, 2); v += __shfl_xor(v, 4);
        if (j == 0) {
            mu_s[n] = mu;
            rs_s[n] = rsqrtf(v * (1.f / HIDDEN) + LN_EPS);
        }
    }
    __syncthreads();

    const float g = gamma[t], bt = beta[t];
    #pragma unroll
    for (int r = 0; r < TILE; ++r) {
        size_t idx = base + (size_t)r * HIDDEN + t;
        float val = (tile[r * HIDDEN + t] - mu_s[r]) * rs_s[r] * g + bt;
        out[idx] = silu_f(val) + h[idx];
    }
}

// global mean pool over sorted batch_ids; one block per graph
__global__ __launch_bounds__(256) void pool_mean(
        const float* __restrict__ h, const int* __restrict__ bid,
        float* __restrict__ out) {
    const int g = blockIdx.x, t = threadIdx.x;
    // lower_bound
    int lo = 0, hi = N_NODES;
    while (lo < hi) { int mid = (lo + hi) >> 1; if (bid[mid] < g) lo = mid + 1; else hi = mid; }
    const int start = lo;
    hi = N_NODES;
    while (lo < hi) { int mid = (lo + hi) >> 1; if (bid[mid] < g + 1) lo = mid + 1; else hi = mid; }
    const int end = lo;
    float s = 0.f;
    for (int n = start; n < end; ++n) s += h[(size_t)n * HIDDEN + t];
    const float cnt = (float)(end - start);
    out[(size_t)g * HIDDEN + t] = s / fmaxf(cnt, 1.f);
}

extern "C" void kernel_launch(void* const* d_in, const int* in_sizes, int n_in,
                              void* d_out, int out_size, void* d_ws, size_t ws_size,
                              hipStream_t stream) {
    const float* x     = (const float*)d_in[0];
    const int*   ei    = (const int*)d_in[1];
    const int*   bid   = (const int*)d_in[2];
    const float* Win   = (const float*)d_in[3];
    const float* bin   = (const float*)d_in[4];
    const float* W     = (const float*)d_in[5];
    const float* b     = (const float*)d_in[6];
    const float* gamma = (const float*)d_in[7];
    const float* beta  = (const float*)d_in[8];
    float* out = (float*)d_out;

    float* A = (float*)d_ws;
    float* B = A + (size_t)N_NODES * HIDDEN;
    const int* src = ei;
    const int* dst = ei + N_EDGES;

    input_proj<<<2048, 256, 0, stream>>>(x, Win, bin, A);

    float* cur = A;
    float* alt = B;
    for (int l = 0; l < N_LAYERS; ++l) {
        hipMemsetAsync(alt, 0, (size_t)N_NODES * HIDDEN * sizeof(float), stream);
        scatter_relu<<<N_EDGES, 256, 0, stream>>>(cur, src, dst, alt);
        gemm_ln<<<N_NODES / TILE, 256, 0, stream>>>(
            cur, alt, W + (size_t)l * HIDDEN * HIDDEN,
            b + (size_t)l * HIDDEN, gamma + (size_t)l * HIDDEN,
            beta + (size_t)l * HIDDEN, alt);
        float* tmp = cur; cur = alt; alt = tmp;
    }
    pool_mean<<<N_GRAPHS, 256, 0, stream>>>(cur, bid, out);
}